// Round 5
// baseline (630.117 us; speedup 1.0000x reference)
//
#include <hip/hip_runtime.h>

#define N_NODES 100000
#define N_EDGES 800000
#define DV 64
#define DE 32
#define DU 32
#define H 128

#define NTILES 12500      // N_EDGES / 64

typedef short bf16x8 __attribute__((ext_vector_type(8)));
typedef unsigned short u16;
typedef u16 u16x8 __attribute__((ext_vector_type(8)));
typedef float f32x4 __attribute__((ext_vector_type(4)));

// ---- workspace layout (bytes) ----
#define OFF_ESUM  0           // [128][16] f32 padded sums
#define OFF_VSUM  8192        // [128][16] f32
#define OFF_PART  16384       // [512] int scan partials
#define OFF_WBUF  18432       // [86016] u16 weights
#define OFF_DEG   190464      // [100000] int degree -> cursor
#define OFF_OFFS  590464      // [100000] int CSR row starts
#define OFF_BUCK  990464      // [800000] int edge ids in dst order
#define OFF_DSTP  4190464     // [800000] int dst per bucket slot
#define OFF_SRCP  7390464     // [800000] int src per bucket slot
#define OFF_EIDXP 10590464    // [800000] int edge_idx per bucket slot
// total ~13.8 MB

// weight sub-offsets (u16 elements within wbuf)
#define W1ET_OFF 0            // [128][192]
#define W2ET_OFF 24576        // [128][128]
#define W1NT_OFF 40960        // [128][224]
#define W2NT_OFF 69632        // [128][128]
#define WBUF_ELEMS 86016

#define NPART 391             // ceil(100000/256)

__device__ inline u16 f2bf(float x) {
  union { float f; unsigned u; } c; c.f = x;
  unsigned r = c.u + 0x7FFFu + ((c.u >> 16) & 1u);   // round-to-nearest-even
  return (u16)(r >> 16);
}

__global__ void prep_weights(const float* __restrict__ W1e, const float* __restrict__ W2e,
                             const float* __restrict__ W1n, const float* __restrict__ W2n,
                             u16* __restrict__ wbuf) {
  int i = blockIdx.x * blockDim.x + threadIdx.x;
  if (i < 24576) {                     // W1e^T [128][192]
    int j = i / 192, k = i - j * 192;
    wbuf[W1ET_OFF + i] = f2bf(W1e[k * H + j]);
  } else if (i < 40960) {              // W2e^T [128][128]
    int t = i - 24576; int j = t >> 7, k = t & 127;
    wbuf[i] = f2bf(W2e[k * H + j]);
  } else if (i < 69632) {              // W1n^T [128][224]
    int t = i - 40960; int j = t / 224, k = t - j * 224;
    wbuf[i] = f2bf(W1n[k * H + j]);
  } else if (i < WBUF_ELEMS) {         // W2n^T [128][128]
    int t = i - 69632; int j = t >> 7, k = t & 127;
    wbuf[i] = f2bf(W2n[k * H + j]);
  }
}

// ---------------- CSR build ----------------
__global__ void degree_kernel(const int* __restrict__ edges, int* __restrict__ deg) {
  int i = blockIdx.x * 256 + threadIdx.x;
  if (i < N_EDGES) atomicAdd(&deg[edges[N_EDGES + i]], 1);
}

__global__ void scan_part(const int* __restrict__ deg, int* __restrict__ part) {
  int i = blockIdx.x * 256 + threadIdx.x;
  int v = (i < N_NODES) ? deg[i] : 0;
#pragma unroll
  for (int m = 1; m < 64; m <<= 1) v += __shfl_xor(v, m);
  __shared__ int s[4];
  if ((threadIdx.x & 63) == 0) s[threadIdx.x >> 6] = v;
  __syncthreads();
  if (threadIdx.x == 0) part[blockIdx.x] = s[0] + s[1] + s[2] + s[3];
}

__global__ void scan_top(int* __restrict__ part) {
  __shared__ int s[512];
  int t = threadIdx.x;
  s[t] = (t < NPART) ? part[t] : 0;
  __syncthreads();
  for (int d = 1; d < 512; d <<= 1) {
    int v = (t >= d) ? s[t - d] : 0;
    __syncthreads();
    s[t] += v;
    __syncthreads();
  }
  if (t < NPART) part[t] = (t == 0) ? 0 : s[t - 1];   // exclusive
}

__global__ void scan_down(const int* __restrict__ part, int* __restrict__ deg_cursor,
                          int* __restrict__ offsets) {
  __shared__ int s[256];
  int b = blockIdx.x, t = threadIdx.x;
  int i = b * 256 + t;
  int v = (i < N_NODES) ? deg_cursor[i] : 0;
  s[t] = v;
  __syncthreads();
  for (int d = 1; d < 256; d <<= 1) {
    int u = (t >= d) ? s[t - d] : 0;
    __syncthreads();
    s[t] += u;
    __syncthreads();
  }
  int excl = s[t] - v + part[b];
  if (i < N_NODES) { offsets[i] = excl; deg_cursor[i] = excl; }  // cursor = start
}

__global__ void fill_kernel(const int* __restrict__ edges, const int* __restrict__ edge_idx,
                            int* __restrict__ cursor, int* __restrict__ bucket,
                            int* __restrict__ dstP, int* __restrict__ srcP,
                            int* __restrict__ eidxP) {
  int i = blockIdx.x * 256 + threadIdx.x;
  if (i < N_EDGES) {
    int s = edges[i];
    int d = edges[N_EDGES + i];
    int pos = atomicAdd(&cursor[d], 1);
    bucket[pos] = i;
    dstP[pos] = d;
    srcP[pos] = s;
    eidxP[pos] = edge_idx[i];
  }
}

// ---- edge kernel: tiles of 64 bucket-ordered edges; fused aggregation ----
__global__ __launch_bounds__(256, 3) void edge_kernel(
    const float* __restrict__ node_attr, const float* __restrict__ edge_attr,
    const float* __restrict__ uattr, const u16* __restrict__ wbuf,
    const float* __restrict__ b1, const float* __restrict__ b2,
    const int* __restrict__ bucket, const int* __restrict__ dstP,
    const int* __restrict__ srcP, const int* __restrict__ eidxP,
    float* __restrict__ e_out, float* __restrict__ agg, float* __restrict__ esum_p)
{
  __shared__ __align__(16) char smem[43008];
  u16 (*X)[200]    = (u16(*)[200])smem;               // 25600 B
  u16 (*Hs)[136]   = (u16(*)[136])(smem + 25600);     // 17408 B
  float (*OT)[132] = (float(*)[132])smem;             // 33792 B overlay (after l2)
  __shared__ int sSrc[64], sDst[64], sEid[64], sEidx[64];

  const int tid = threadIdx.x;
  const int wave = tid >> 6, lane = tid & 63;
  const int l15 = lane & 15, lg = lane >> 4;
  const int wc = wave * 32;

  // bijective XCD-chunk swizzle (m204): XCD b%8 gets a contiguous tile chunk
  int b = blockIdx.x;
  const int q = NTILES / 8, r8 = NTILES % 8;
  int xcd = b & 7, pos = b >> 3;
  long t = (xcd < r8 ? xcd * (q + 1) : r8 * (q + 1) + (xcd - r8) * q) + pos;
  const long i0 = t * 64;

  if (tid < 64)        sSrc[tid]        = srcP[i0 + tid];
  else if (tid < 128)  sDst[tid - 64]   = dstP[i0 + (tid - 64)];
  else if (tid < 192)  sEid[tid - 128]  = bucket[i0 + (tid - 128)];
  else                 sEidx[tid - 192] = eidxP[i0 + (tid - 192)];

  // per-wave weight slices in registers
  bf16x8 w1[6][2], w2[4][2];
  {
    const u16* w1t = wbuf + W1ET_OFF;
    const u16* w2t = wbuf + W2ET_OFF;
#pragma unroll
    for (int cf = 0; cf < 2; ++cf) {
      const u16* p1 = w1t + (wc + cf * 16 + l15) * 192 + lg * 8;
#pragma unroll
      for (int ks = 0; ks < 6; ++ks) w1[ks][cf] = *(const bf16x8*)(p1 + ks * 32);
      const u16* p2 = w2t + (wc + cf * 16 + l15) * 128 + lg * 8;
#pragma unroll
      for (int ks = 0; ks < 4; ++ks) w2[ks][cf] = *(const bf16x8*)(p2 + ks * 32);
    }
  }

  __syncthreads();

  // stage X: 64 rows x 192 cols of bf16 -> 1536 chunks, 6/thread
#pragma unroll
  for (int it = 0; it < 6; ++it) {
    int ch = tid + it * 256;
    int r = ch / 24, seg = ch - r * 24;
    int col = seg * 8;
    const float* src;
    if (col < 64)        src = node_attr + (long)sSrc[r] * DV + col;
    else if (col < 128)  src = node_attr + (long)sDst[r] * DV + (col - 64);
    else if (col < 160)  src = edge_attr + (long)sEid[r] * DE + (col - 128);
    else                 src = uattr + (long)sEidx[r] * DU + (col - 160);
    float4 f0 = *(const float4*)src;
    float4 f1 = *(const float4*)(src + 4);
    u16x8 p;
    p[0] = f2bf(f0.x); p[1] = f2bf(f0.y); p[2] = f2bf(f0.z); p[3] = f2bf(f0.w);
    p[4] = f2bf(f1.x); p[5] = f2bf(f1.y); p[6] = f2bf(f1.z); p[7] = f2bf(f1.w);
    *(u16x8*)&X[r][col] = p;
  }

  __syncthreads();

  f32x4 acc[4][2];
#pragma unroll
  for (int rf = 0; rf < 4; ++rf)
#pragma unroll
    for (int cf = 0; cf < 2; ++cf)
#pragma unroll
      for (int j = 0; j < 4; ++j) acc[rf][cf][j] = 0.f;

  // layer 1: [64,192] @ [192,128]
#pragma unroll
  for (int ks = 0; ks < 6; ++ks) {
#pragma unroll
    for (int rf = 0; rf < 4; ++rf) {
      bf16x8 a = *(const bf16x8*)&X[rf * 16 + l15][ks * 32 + lg * 8];
      acc[rf][0] = __builtin_amdgcn_mfma_f32_16x16x32_bf16(a, w1[ks][0], acc[rf][0], 0, 0, 0);
      acc[rf][1] = __builtin_amdgcn_mfma_f32_16x16x32_bf16(a, w1[ks][1], acc[rf][1], 0, 0, 0);
    }
  }

  float bias1[2] = { b1[wc + l15], b1[wc + 16 + l15] };
#pragma unroll
  for (int rf = 0; rf < 4; ++rf)
#pragma unroll
    for (int cf = 0; cf < 2; ++cf)
#pragma unroll
      for (int j = 0; j < 4; ++j) {
        float hv = acc[rf][cf][j] + bias1[cf];
        hv = hv > 0.f ? hv : 0.f;
        Hs[rf * 16 + lg * 4 + j][wc + cf * 16 + l15] = f2bf(hv);
      }

  __syncthreads();

#pragma unroll
  for (int rf = 0; rf < 4; ++rf)
#pragma unroll
    for (int cf = 0; cf < 2; ++cf)
#pragma unroll
      for (int j = 0; j < 4; ++j) acc[rf][cf][j] = 0.f;

  // layer 2: [64,128] @ [128,128]
#pragma unroll
  for (int ks = 0; ks < 4; ++ks) {
#pragma unroll
    for (int rf = 0; rf < 4; ++rf) {
      bf16x8 a = *(const bf16x8*)&Hs[rf * 16 + l15][ks * 32 + lg * 8];
      acc[rf][0] = __builtin_amdgcn_mfma_f32_16x16x32_bf16(a, w2[ks][0], acc[rf][0], 0, 0, 0);
      acc[rf][1] = __builtin_amdgcn_mfma_f32_16x16x32_bf16(a, w2[ks][1], acc[rf][1], 0, 0, 0);
    }
  }

  __syncthreads();   // Hs reads done before OT overwrite

  float bias2[2] = { b2[wc + l15], b2[wc + 16 + l15] };
  float es0 = 0.f, es1 = 0.f;
#pragma unroll
  for (int rf = 0; rf < 4; ++rf) {
#pragma unroll
    for (int cf = 0; cf < 2; ++cf) {
#pragma unroll
      for (int j = 0; j < 4; ++j) {
        float v = acc[rf][cf][j] + bias2[cf];
        OT[rf * 16 + lg * 4 + j][wc + cf * 16 + l15] = v;
        if (cf == 0) es0 += v; else es1 += v;
      }
    }
  }

  __syncthreads();   // OT + sDst ready

  if (tid < 128) {
    // ---- fused aggregation: per-column segmented scan over dst-sorted rows ----
    const int c = tid;
    float sum = OT[0][c];
    int runStart = 0;
    int dprev = sDst[0];
    for (int r = 1; r < 64; ++r) {
      int d = sDst[r];                        // wave-uniform -> no divergence
      if (d != dprev) {
        if (runStart == 0) atomicAdd(&agg[(long)dprev * H + c], sum);
        else               agg[(long)dprev * H + c] = sum;   // exclusive run
        runStart = r; sum = 0.f; dprev = d;
      }
      sum += OT[r][c];
    }
    atomicAdd(&agg[(long)dprev * H + c], sum); // boundary run
  } else {
    // ---- e_out row stores (rows scattered, 512 B contiguous each) ----
#pragma unroll
    for (int i = 0; i < 16; ++i) {
      int ch = (tid - 128) + i * 128;
      int r = ch >> 5, c4 = ch & 31;
      float4 f = *(const float4*)&OT[r][c4 * 4];
      *(float4*)(e_out + (long)sEid[r] * H + c4 * 4) = f;
    }
  }

#pragma unroll
  for (int m = 16; m < 64; m <<= 1) { es0 += __shfl_xor(es0, m); es1 += __shfl_xor(es1, m); }
  if (lane < 16) {
    atomicAdd(&esum_p[(wc + lane) * 16], es0);
    atomicAdd(&esum_p[(wc + 16 + lane) * 16], es1);
  }
}

// ---- node kernel: pure sequential-read MLP; agg read in place from v region ----
__global__ __launch_bounds__(256, 3) void node_kernel(
    const float* __restrict__ node_attr, const float* __restrict__ uattr,
    const int* __restrict__ node_idx, const u16* __restrict__ wbuf,
    const float* __restrict__ b1, const float* __restrict__ b2,
    float* __restrict__ vio, float* __restrict__ vsum_p)
{
  __shared__ __align__(16) u16 X[64][232];    // 224 cols + pad
  __shared__ __align__(16) u16 Hs[64][136];

  const int tid = threadIdx.x;
  const int wave = tid >> 6, lane = tid & 63;
  const int l15 = lane & 15, lg = lane >> 4;
  const long n0 = (long)blockIdx.x * 64;
  const int wc = wave * 32;

  // stage X: cols 0-63 node_attr, 64-191 agg (in v region), 192-223 u
#pragma unroll
  for (int it = 0; it < 7; ++it) {
    int ch = tid + it * 256;
    int r = ch / 28, seg = ch - r * 28;
    int col = seg * 8;
    long n = n0 + r; if (n >= N_NODES) n = N_NODES - 1;   // clamp tail
    const float* src;
    if (col < 64)        src = node_attr + n * DV + col;
    else if (col < 192)  src = vio + n * H + (col - 64);
    else                 src = uattr + (long)node_idx[n] * DU + (col - 192);
    float4 f0 = *(const float4*)src;
    float4 f1 = *(const float4*)(src + 4);
    u16x8 p;
    p[0] = f2bf(f0.x); p[1] = f2bf(f0.y); p[2] = f2bf(f0.z); p[3] = f2bf(f0.w);
    p[4] = f2bf(f1.x); p[5] = f2bf(f1.y); p[6] = f2bf(f1.z); p[7] = f2bf(f1.w);
    *(u16x8*)&X[r][col] = p;
  }

  // per-wave weight slices
  bf16x8 w1[7][2], w2[4][2];
  {
    const u16* w1t = wbuf + W1NT_OFF;
    const u16* w2t = wbuf + W2NT_OFF;
#pragma unroll
    for (int cf = 0; cf < 2; ++cf) {
      const u16* p1 = w1t + (wc + cf * 16 + l15) * 224 + lg * 8;
#pragma unroll
      for (int ks = 0; ks < 7; ++ks) w1[ks][cf] = *(const bf16x8*)(p1 + ks * 32);
      const u16* p2 = w2t + (wc + cf * 16 + l15) * 128 + lg * 8;
#pragma unroll
      for (int ks = 0; ks < 4; ++ks) w2[ks][cf] = *(const bf16x8*)(p2 + ks * 32);
    }
  }

  __syncthreads();

  f32x4 acc[4][2];
#pragma unroll
  for (int rf = 0; rf < 4; ++rf)
#pragma unroll
    for (int cf = 0; cf < 2; ++cf)
#pragma unroll
      for (int j = 0; j < 4; ++j) acc[rf][cf][j] = 0.f;

#pragma unroll
  for (int ks = 0; ks < 7; ++ks) {
#pragma unroll
    for (int rf = 0; rf < 4; ++rf) {
      bf16x8 a = *(const bf16x8*)&X[rf * 16 + l15][ks * 32 + lg * 8];
      acc[rf][0] = __builtin_amdgcn_mfma_f32_16x16x32_bf16(a, w1[ks][0], acc[rf][0], 0, 0, 0);
      acc[rf][1] = __builtin_amdgcn_mfma_f32_16x16x32_bf16(a, w1[ks][1], acc[rf][1], 0, 0, 0);
    }
  }

  float bias1[2] = { b1[wc + l15], b1[wc + 16 + l15] };
#pragma unroll
  for (int rf = 0; rf < 4; ++rf)
#pragma unroll
    for (int cf = 0; cf < 2; ++cf)
#pragma unroll
      for (int j = 0; j < 4; ++j) {
        float hv = acc[rf][cf][j] + bias1[cf];
        hv = hv > 0.f ? hv : 0.f;
        Hs[rf * 16 + lg * 4 + j][wc + cf * 16 + l15] = f2bf(hv);
      }

  __syncthreads();

#pragma unroll
  for (int rf = 0; rf < 4; ++rf)
#pragma unroll
    for (int cf = 0; cf < 2; ++cf)
#pragma unroll
      for (int j = 0; j < 4; ++j) acc[rf][cf][j] = 0.f;

#pragma unroll
  for (int ks = 0; ks < 4; ++ks) {
#pragma unroll
    for (int rf = 0; rf < 4; ++rf) {
      bf16x8 a = *(const bf16x8*)&Hs[rf * 16 + l15][ks * 32 + lg * 8];
      acc[rf][0] = __builtin_amdgcn_mfma_f32_16x16x32_bf16(a, w2[ks][0], acc[rf][0], 0, 0, 0);
      acc[rf][1] = __builtin_amdgcn_mfma_f32_16x16x32_bf16(a, w2[ks][1], acc[rf][1], 0, 0, 0);
    }
  }

  float bias2[2] = { b2[wc + l15], b2[wc + 16 + l15] };
  float vs0 = 0.f, vs1 = 0.f;
#pragma unroll
  for (int rf = 0; rf < 4; ++rf) {
#pragma unroll
    for (int cf = 0; cf < 2; ++cf) {
      int colg = wc + cf * 16 + l15;
#pragma unroll
      for (int j = 0; j < 4; ++j) {
        int r = rf * 16 + lg * 4 + j;
        long n = n0 + r;
        if (n < N_NODES) {
          float v = acc[rf][cf][j] + bias2[cf];
          vio[n * H + colg] = v;   // in-place overwrite of agg (reads done pre-barrier)
          if (cf == 0) vs0 += v; else vs1 += v;
        }
      }
    }
  }
#pragma unroll
  for (int m = 16; m < 64; m <<= 1) { vs0 += __shfl_xor(vs0, m); vs1 += __shfl_xor(vs1, m); }
  if (lane < 16) {
    atomicAdd(&vsum_p[(wc + lane) * 16], vs0);
    atomicAdd(&vsum_p[(wc + 16 + lane) * 16], vs1);
  }
}

// ---------------- global kernel: G=1, f32 precision ----------------
__global__ void global_kernel(const float* __restrict__ uattr,
    const float* __restrict__ W1g, const float* __restrict__ b1g,
    const float* __restrict__ W2g, const float* __restrict__ b2g,
    const float* __restrict__ esum_p, const float* __restrict__ vsum_p,
    float* __restrict__ g_out)
{
  __shared__ float gin[288];
  __shared__ float hbuf[128];
  int t = threadIdx.x;   // 128 threads
  gin[t]       = vsum_p[t * 16] * (1.f / (float)N_NODES);
  gin[128 + t] = esum_p[t * 16] * (1.f / (float)N_EDGES);
  if (t < 32) gin[256 + t] = uattr[t];
  __syncthreads();
  float a = b1g[t];
  for (int k = 0; k < 288; ++k) a += gin[k] * W1g[k * H + t];
  hbuf[t] = fmaxf(a, 0.f);
  __syncthreads();
  float b = b2g[t];
  for (int k = 0; k < 128; ++k) b += hbuf[k] * W2g[k * H + t];
  g_out[t] = b;
}

extern "C" void kernel_launch(void* const* d_in, const int* in_sizes, int n_in,
                              void* d_out, int out_size, void* d_ws, size_t ws_size,
                              hipStream_t stream) {
  const float* node_attr = (const float*)d_in[0];
  const int*   edges     = (const int*)d_in[1];
  const float* edge_attr = (const float*)d_in[2];
  const float* uattr     = (const float*)d_in[3];
  const int*   node_idx  = (const int*)d_in[4];
  const int*   edge_idx  = (const int*)d_in[5];
  const float* W1e = (const float*)d_in[6];  const float* b1e = (const float*)d_in[7];
  const float* W2e = (const float*)d_in[8];  const float* b2e = (const float*)d_in[9];
  const float* W1n = (const float*)d_in[10]; const float* b1n = (const float*)d_in[11];
  const float* W2n = (const float*)d_in[12]; const float* b2n = (const float*)d_in[13];
  const float* W1g = (const float*)d_in[14]; const float* b1g = (const float*)d_in[15];
  const float* W2g = (const float*)d_in[16]; const float* b2g = (const float*)d_in[17];

  float* out   = (float*)d_out;
  float* v_out = out;                                          // [N,H] (agg first)
  float* e_out = out + (long)N_NODES * H;                      // [E,H]
  float* g_out = out + (long)N_NODES * H + (long)N_EDGES * H;  // [G,H]

  char* ws = (char*)d_ws;
  float* esum_p = (float*)(ws + OFF_ESUM);
  float* vsum_p = (float*)(ws + OFF_VSUM);
  int*   part   = (int*)(ws + OFF_PART);
  u16*   wbuf   = (u16*)(ws + OFF_WBUF);
  int*   deg    = (int*)(ws + OFF_DEG);     // becomes cursor after scan_down
  int*   offs   = (int*)(ws + OFF_OFFS);
  int*   buck   = (int*)(ws + OFF_BUCK);
  int*   dstP   = (int*)(ws + OFF_DSTP);
  int*   srcP   = (int*)(ws + OFF_SRCP);
  int*   eidxP  = (int*)(ws + OFF_EIDXP);

  hipMemsetAsync(ws, 0, 16384, stream);                   // esum_p + vsum_p
  hipMemsetAsync(deg, 0, N_NODES * sizeof(int), stream);  // degrees
  hipMemsetAsync(v_out, 0, (size_t)N_NODES * H * sizeof(float), stream);  // agg init

  prep_weights<<<WBUF_ELEMS / 256, 256, 0, stream>>>(W1e, W2e, W1n, W2n, wbuf);
  degree_kernel<<<(N_EDGES + 255) / 256, 256, 0, stream>>>(edges, deg);
  scan_part<<<NPART, 256, 0, stream>>>(deg, part);
  scan_top<<<1, 512, 0, stream>>>(part);
  scan_down<<<NPART, 256, 0, stream>>>(part, deg, offs);
  fill_kernel<<<(N_EDGES + 255) / 256, 256, 0, stream>>>(edges, edge_idx, deg,
                                                         buck, dstP, srcP, eidxP);

  edge_kernel<<<NTILES, 256, 0, stream>>>(node_attr, edge_attr, uattr, wbuf,
                                          b1e, b2e, buck, dstP, srcP, eidxP,
                                          e_out, v_out, esum_p);
  node_kernel<<<(N_NODES + 63) / 64, 256, 0, stream>>>(node_attr, uattr, node_idx,
                                                       wbuf, b1n, b2n, v_out, vsum_p);
  global_kernel<<<1, 128, 0, stream>>>(uattr, W1g, b1g, W2g, b2g, esum_p, vsum_p, g_out);
}